// Round 13
// baseline (126.539 us; speedup 1.0000x reference)
//
#include <hip/hip_runtime.h>

#define T_LEN 256
#define NG 31              // 31 groups x 16 steps = 496 (need s_max = 487)
#define K_SKEW 31          // per-seam schedule offset (16 layers + delay 17 - 2)

__device__ __forceinline__ float ex2(float x) { return __builtin_amdgcn_exp2f(x); }
__device__ __forceinline__ float rcp1p(float e) { return __builtin_amdgcn_rcpf(1.0f + e); }

// row_shr:1 (0x111): lane i <- lane i-1 within each 16-lane row; lanes
// 0,16,32,48 keep their own value. Replicates a 16-lane pipeline 4x.
__device__ __forceinline__ float dpp_row_shr1(float v) {
    int i = __float_as_int(v);
    return __int_as_float(__builtin_amdgcn_update_dpp(i, i, 0x111, 0xF, 0xF, false));
}
// wave_rol:1 (0x134): lane i <- lane (i+1)%64 (output conveyor).
__device__ __forceinline__ float dpp_wave_rol1(float v) {
    int i = __float_as_int(v);
    return __int_as_float(__builtin_amdgcn_update_dpp(i, i, 0x134, 0xF, 0xF, false));
}

// EIGHT waves (2 per SIMD => chain stalls of one wave filled by the other),
// 16 layers/wave: layer L = 16*wv + j, j = lane & 15; lanes 16-63 are exact
// replicas of lanes 0-15 (row_shr:1 handoff + shared (lane&15)-indexed params),
// so all lanes compute real layers and ring writes are identical-value.
// Schedule: cell (L,t) at step s = t + j + K_SKEW*wv.
//  - in-row handoff: DPP row_shr:1 (prev-step h). Exact.
//  - seam (16wv-1 -> 16wv): wave wv-1's j=15 h, produced at step s-17. Each
//    wave writes plane[wv][s&63][j] (4 replica lanes, same value). Consumer
//    prefetches slots (16g+k-17)&63 at group top (all written before the
//    previous barrier since k-17 <= -2; overwrite at +64 > barrier-drift
//    window 48 => race-free by barriers alone).
//  - wave0 seam feed = x[s] via identical group-top broadcast reads of sx.
//  - R12 folded cell: h' = s_n*(2-2z) + (z*h + z-1); z:=1 freeze when t
//    invalid => h'==h exactly (ramp in/out state-exact; planes zero-inited).
//  - output: conveyor on wave7 (inject layer-127 h at lane 63, wave_rol:1),
//    coalesced 64-lane stores at s = 295,359,423,487 (k==7, g=18,22,26,30).
__global__ __launch_bounds__(512, 1) void gru_stack_wavefront(
    const float* __restrict__ x,
    const float* __restrict__ w_ih,
    const float* __restrict__ w_hh,
    const float* __restrict__ b_ih,
    const float* __restrict__ b_hh,
    float* __restrict__ out)
{
    __shared__ float plane[8][64 * 16];   // per-wave ring [slot][j], 32 KiB
    __shared__ float sx[T_LEN];
    const int tid  = threadIdx.x;         // 0..511
    const int lane = tid & 63;
    const int wv   = tid >> 6;            // 0..7
    const int j    = lane & 15;           // layer-within-wave
    const int L    = 16 * wv + j;         // global layer 0..127

    if (tid < T_LEN) sx[tid] = x[tid];
    #pragma unroll
    for (int m = tid; m < 8 * 64 * 16; m += 512) (&plane[0][0])[m] = 0.0f;

    const float L1 = -1.4426950408889634f;   // -log2(e)
    const float L2 = -2.8853900817779268f;   // -2*log2(e)

    const float wi_r = L1 * w_ih[3 * L + 0], wh_r = L1 * w_hh[3 * L + 0];
    const float b_r  = L1 * (b_ih[3 * L + 0] + b_hh[3 * L + 0]);
    const float wi_z = L1 * w_ih[3 * L + 1], wh_z = L1 * w_hh[3 * L + 1];
    const float b_z  = L1 * (b_ih[3 * L + 1] + b_hh[3 * L + 1]);
    const float wi_n = L2 * w_ih[3 * L + 2], bi_n = L2 * b_ih[3 * L + 2];
    const float wh_n = L2 * w_hh[3 * L + 2], bh_n = L2 * b_hh[3 * L + 2];

    float h = 0.0f;
    float c_r = b_r, c_z = b_z, g_n = bh_n;  // h-dependent precomputes (h=0)

    float pk[16];
    float ov = 0.0f;                      // output conveyor (only wave7's used)
    int t = -j - K_SKEW * wv - 1;         // ++ at step top -> t = s - j - 31*wv

    const bool is_j0 = (j == 0);
    const bool is_w0 = (wv == 0);
    const bool is_w7 = (wv == 7);
    float* myplane = plane[wv];
    const float* srcplane = plane[wv == 0 ? 0 : wv - 1];

    __syncthreads();                      // sx + plane init visible

    for (int g = 0; g < NG; ++g) {
        const int sb = 16 * g;

        // group-top seam prefetch (broadcast reads, consumed this group)
        if (is_w0) {
            #pragma unroll
            for (int k = 0; k < 16; ++k)
                pk[k] = sx[(sb + k) & (T_LEN - 1)];            // x[s] (gated >255)
        } else {
            #pragma unroll
            for (int k = 0; k < 16; ++k)
                pk[k] = srcplane[((sb + k - 17) & 63) * 16 + 15];  // h(16wv-1, .)
        }

        #pragma unroll
        for (int k = 0; k < 16; ++k) {
            ++t;
            const bool valid = (unsigned)t < (unsigned)T_LEN;

            // handoff: replicated 16-lane pipeline; row heads take seam feed
            float shifted = dpp_row_shr1(h);
            float in = is_j0 ? pk[k] : shifted;

            // R12 folded GRU cell
            float u_r  = fmaf(wi_r, in, c_r);
            float u_z  = fmaf(wi_z, in, c_z);
            float u_n0 = fmaf(wi_n, in, bi_n);
            float r = rcp1p(ex2(u_r));
            float z = rcp1p(ex2(u_z));
            z = valid ? z : 1.0f;                    // freeze: h' == h exactly
            float two_omz = fmaf(-2.0f, z, 2.0f);    // 2*(1-z), off-chain
            float zh_m    = fmaf(z, h, z - 1.0f);    // z*h - (1-z), off-chain
            float s_n = rcp1p(ex2(fmaf(r, g_n, u_n0)));
            h = fmaf(s_n, two_omz, zh_m);            // (1-z)*(2*s_n-1) + z*h

            c_r = fmaf(wh_r, h, b_r);                // off input-critical chain
            c_z = fmaf(wh_z, h, b_z);
            g_n = fmaf(wh_n, h, bh_n);

            myplane[((sb + k) & 63) * 16 + j] = h;   // publish (replica-identical)

            // output conveyor: rotate, inject layer-127 h at lane 63 (wave7)
            float rot = dpp_wave_rol1(ov);
            ov = (lane == 63) ? h : rot;

            if (k == 7 && is_w7 && g >= 18 && ((g - 18) & 3) == 0)
                out[sb - 288 + lane] = ov;           // s = 295,359,423,487
        }
        __syncthreads();                             // bounds wave drift (<16 steps)
    }
}

extern "C" void kernel_launch(void* const* d_in, const int* in_sizes, int n_in,
                              void* d_out, int out_size, void* d_ws, size_t ws_size,
                              hipStream_t stream) {
    const float* x    = (const float*)d_in[0];  // [1,256]
    const float* w_ih = (const float*)d_in[1];  // [128,3,1]
    const float* w_hh = (const float*)d_in[2];  // [128,3,1]
    const float* b_ih = (const float*)d_in[3];  // [128,3]
    const float* b_hh = (const float*)d_in[4];  // [128,3]
    float* out = (float*)d_out;                 // [1,256]

    gru_stack_wavefront<<<1, 512, 0, stream>>>(x, w_ih, w_hh, b_ih, b_hh, out);
}

// Round 14
// 100.468 us; speedup vs baseline: 1.2595x; 1.2595x over previous
//
#include <hip/hip_runtime.h>

#define T_LEN 256
#define NG 26              // 26 groups x 16 steps = 416 steps (need 415: s_max=414)

__device__ __forceinline__ float ex2(float x) { return __builtin_amdgcn_exp2f(x); }
__device__ __forceinline__ float rcp1p(float e) { return __builtin_amdgcn_rcpf(1.0f + e); }

// wave_shr:1 (0x138): lane i <- lane i-1 (lane 0 keeps own). VALU pipe.
__device__ __forceinline__ float dpp_wave_shr1(float v) {
    int i = __float_as_int(v);
    return __int_as_float(__builtin_amdgcn_update_dpp(i, i, 0x138, 0xF, 0xF, false));
}
// wave_rol:1 (0x134): lane i <- lane (i+1)%64.
__device__ __forceinline__ float dpp_wave_rol1(float v) {
    int i = __float_as_int(v);
    return __int_as_float(__builtin_amdgcn_update_dpp(i, i, 0x134, 0xF, 0xF, false));
}

// R12 skeleton (best measured: ~222 cyc/step), R14 = pure issue deletions:
//  - ring written by WAVE 0 ONLY (plane 1 was never read)        [-7 cyc w1]
//  - single-buffer seam: pk[k] = ring slot (16g+k-33) read at group top,
//    consumed this group (drop pnext->pcur copy)                 [-2 cyc w1]
//    hazard: slot written >=18 steps before previous barrier; overwrite at
//    step 16g+k+31 is in w0's group g+1, blocked by end-of-g barrier.
//  - output conveyor runs on WAVE 1 ONLY                         [-4 cyc w0]
// TWO waves, 1 layer/lane. cell (l,t) at step s = t + l + 32*(l>=64).
//  - in-wave handoff: DPP wave_shr:1 (exact, prev-step h).
//  - folded h-update: h' = s_n*(2-2z) + (z*h + z-1); two_omz/zh_m off-chain.
//  - validity z:=1 freeze => h'==h exactly (ring zero-inited; no NaN).
//  - x reaches wave0 lane0 via a wave_rol:1 register conveyor (4 chunks).
//  - out: conveyor on w1 (inject layer-127 h at lane 63), coalesced 64-lane
//    stores at s=222,286,350,414 (k==14, g=13,17,21,25).
__global__ __launch_bounds__(128, 1) void gru_stack_wavefront(
    const float* __restrict__ x,
    const float* __restrict__ w_ih,
    const float* __restrict__ w_hh,
    const float* __restrict__ b_ih,
    const float* __restrict__ b_hh,
    float* __restrict__ out)
{
    __shared__ float ring[64 * 64];       // wave0 h history [slot][lane], 16 KiB
    const int tid  = threadIdx.x;         // 0..127 == layer index
    const int lane = tid & 63;
    const int wid  = tid >> 6;

    #pragma unroll 4
    for (int m = tid; m < 64 * 64; m += 128) ring[m] = 0.0f;

    const float L1 = -1.4426950408889634f;   // -log2(e)
    const float L2 = -2.8853900817779268f;   // -2*log2(e)

    const float wi_r = L1 * w_ih[3 * tid + 0], wh_r = L1 * w_hh[3 * tid + 0];
    const float b_r  = L1 * (b_ih[3 * tid + 0] + b_hh[3 * tid + 0]);
    const float wi_z = L1 * w_ih[3 * tid + 1], wh_z = L1 * w_hh[3 * tid + 1];
    const float b_z  = L1 * (b_ih[3 * tid + 1] + b_hh[3 * tid + 1]);
    const float wi_n = L2 * w_ih[3 * tid + 2], bi_n = L2 * b_ih[3 * tid + 2];
    const float wh_n = L2 * w_hh[3 * tid + 2], bh_n = L2 * b_hh[3 * tid + 2];

    float xc0 = x[lane];
    float xc1 = x[lane + 64];
    float xc2 = x[lane + 128];
    float xc3 = x[lane + 192];

    float h = 0.0f;
    float c_r = b_r, c_z = b_z, g_n = bh_n;

    float pk[16];
    #pragma unroll
    for (int k = 0; k < 16; ++k) pk[k] = 0.0f;

    float ov = 0.0f;                      // output conveyor (wave1)
    float xq = xc0;                       // x conveyor (wave0)
    int t = -lane - 96 * wid - 1;         // ++ at step top -> t = s - lane - 96*wid

    const bool is_l0 = (lane == 0);
    const bool is_w0 = (wid == 0);
    const bool is_w1 = !is_w0;

    __syncthreads();                      // ring init visible

    for (int g = 0; g < NG; ++g) {
        if      (g == 4)  xq = xc1;       // chunk switch at s = 64,128,192
        else if (g == 8)  xq = xc2;
        else if (g == 12) xq = xc3;

        if (is_w1) {                      // seam prefetch: consumed THIS group
            #pragma unroll
            for (int k = 0; k < 16; ++k)
                pk[k] = ring[((16 * g + k - 33) & 63) * 64 + 63];   // h(63, .)
        }

        const int sb = (16 * g) & 63;     // slot base for this group

        #pragma unroll
        for (int k = 0; k < 16; ++k) {
            ++t;
            const bool valid = (unsigned)t < (unsigned)T_LEN;

            float alt = is_w1 ? pk[k] : xq;          // ready since group top
            float shifted = dpp_wave_shr1(h);        // chain start
            float in = is_l0 ? alt : shifted;

            float u_r  = fmaf(wi_r, in, c_r);
            float u_z  = fmaf(wi_z, in, c_z);
            float u_n0 = fmaf(wi_n, in, bi_n);
            float r = rcp1p(ex2(u_r));
            float z = rcp1p(ex2(u_z));
            z = valid ? z : 1.0f;                    // freeze: two_omz=0, zh_m=h
            float two_omz = fmaf(-2.0f, z, 2.0f);    // 2*(1-z), off-chain
            float zh_m    = fmaf(z, h, z - 1.0f);    // z*h - (1-z), off-chain
            float s_n = rcp1p(ex2(fmaf(r, g_n, u_n0)));
            h = fmaf(s_n, two_omz, zh_m);            // (1-z)*(2*s_n-1) + z*h

            c_r = fmaf(wh_r, h, b_r);                // off input-critical chain
            c_z = fmaf(wh_z, h, b_z);
            g_n = fmaf(wh_n, h, bh_n);

            if (is_w0) {
                ring[((sb + k) & 63) * 64 + lane] = h;   // publish (w0 only)
                xq = dpp_wave_rol1(xq);                  // x conveyor advance
            } else {
                // output conveyor: rotate, inject layer-127 h at lane 63
                float rot = dpp_wave_rol1(ov);
                ov = (lane == 63) ? h : rot;
                if (k == 14 && (g & 3) == 1 && g >= 13)
                    out[16 * g - 208 + lane] = ov;       // s = 222,286,350,414
            }
        }
        __syncthreads();                             // bounds wave drift (<16 steps)
    }
}

extern "C" void kernel_launch(void* const* d_in, const int* in_sizes, int n_in,
                              void* d_out, int out_size, void* d_ws, size_t ws_size,
                              hipStream_t stream) {
    const float* x    = (const float*)d_in[0];  // [1,256]
    const float* w_ih = (const float*)d_in[1];  // [128,3,1]
    const float* w_hh = (const float*)d_in[2];  // [128,3,1]
    const float* b_ih = (const float*)d_in[3];  // [128,3]
    const float* b_hh = (const float*)d_in[4];  // [128,3]
    float* out = (float*)d_out;                 // [1,256]

    gru_stack_wavefront<<<1, 128, 0, stream>>>(x, w_ih, w_hh, b_ih, b_hh, out);
}

// Round 15
// 94.338 us; speedup vs baseline: 1.3413x; 1.0650x over previous
//
#include <hip/hip_runtime.h>

#define T_LEN 256
#define NG 25              // 25 groups x 16 steps = 400 steps (need s_max = 398)

__device__ __forceinline__ float ex2(float x) { return __builtin_amdgcn_exp2f(x); }
__device__ __forceinline__ float rcp1p(float e) { return __builtin_amdgcn_rcpf(1.0f + e); }

// wave_shr:1 (0x138): lane i <- lane i-1 (lane 0 keeps own). VALU pipe.
__device__ __forceinline__ float dpp_wave_shr1(float v) {
    int i = __float_as_int(v);
    return __int_as_float(__builtin_amdgcn_update_dpp(i, i, 0x138, 0xF, 0xF, false));
}
// wave_rol:1 (0x134): lane i <- lane (i+1)%64.
__device__ __forceinline__ float dpp_wave_rol1(float v) {
    int i = __float_as_int(v);
    return __int_as_float(__builtin_amdgcn_update_dpp(i, i, 0x134, 0xF, 0xF, false));
}

// R12 skeleton with ONE change: seam delay 33 -> 17 (single-buffer prefetch
// consumed in the SAME group), so wave-1 offset 96 -> 80 and steps 416 -> 400.
// TWO waves, 1 layer/lane. cell (l,t) at step s = t + l + 16*(l>=64).
//  - in-wave handoff: DPP wave_shr:1 (exact, prev-step h).
//  - cross-wave (63->64): w1 lane0 at step s needs h(63, s-80), produced at
//    step s-17. Group-top prefetch of slots (16g+k-17)&63, k=0..15 — all
//    written before the end-of-(g-1) barrier (k-17 <= -2); mod-64 the read
//    slots (47..62 rel) are disjoint from w0's group-g writes (0..15 rel);
//    overwrite of a read slot is >=2 groups later, barrier-blocked. Exact.
//  - BOTH waves run the full branch-free body (R11/R14 lesson: wave-
//    specialized branches in the unrolled loop cost more than they save).
//  - folded h-update: h' = s_n*(2-2z) + (z*h + z-1); two_omz/zh_m off-chain.
//  - validity z:=1 freeze => h'==h exactly (ring zero-inited; no NaN).
//  - x conveyor (wave_rol:1, 4 chunks, switch at g=4,8,12); output conveyor
//    injects layer-127 h at lane 63; coalesced 64-lane stores at
//    s = 206,270,334,398 (k==14, g=12,16,20,24), out base = 16g-192.
__global__ __launch_bounds__(128, 1) void gru_stack_wavefront(
    const float* __restrict__ x,
    const float* __restrict__ w_ih,
    const float* __restrict__ w_hh,
    const float* __restrict__ b_ih,
    const float* __restrict__ b_hh,
    float* __restrict__ out)
{
    __shared__ float ring[2 * 64 * 64];   // [wid][slot][lane], 32 KiB
    const int tid  = threadIdx.x;         // 0..127 == layer index
    const int lane = tid & 63;
    const int wid  = tid >> 6;

    #pragma unroll 4
    for (int m = tid; m < 2 * 64 * 64; m += 128) ring[m] = 0.0f;

    const float L1 = -1.4426950408889634f;   // -log2(e)
    const float L2 = -2.8853900817779268f;   // -2*log2(e)

    const float wi_r = L1 * w_ih[3 * tid + 0], wh_r = L1 * w_hh[3 * tid + 0];
    const float b_r  = L1 * (b_ih[3 * tid + 0] + b_hh[3 * tid + 0]);
    const float wi_z = L1 * w_ih[3 * tid + 1], wh_z = L1 * w_hh[3 * tid + 1];
    const float b_z  = L1 * (b_ih[3 * tid + 1] + b_hh[3 * tid + 1]);
    const float wi_n = L2 * w_ih[3 * tid + 2], bi_n = L2 * b_ih[3 * tid + 2];
    const float wh_n = L2 * w_hh[3 * tid + 2], bh_n = L2 * b_hh[3 * tid + 2];

    float xc0 = x[lane];
    float xc1 = x[lane + 64];
    float xc2 = x[lane + 128];
    float xc3 = x[lane + 192];

    float h = 0.0f;
    float c_r = b_r, c_z = b_z, g_n = bh_n;

    float pk[16];
    #pragma unroll
    for (int k = 0; k < 16; ++k) pk[k] = 0.0f;

    float ov = 0.0f;                      // output conveyor (wave1's is stored)
    float xq = xc0;                       // x conveyor (wave0's is consumed)
    int t = -lane - 80 * wid - 1;         // ++ at step top -> t = s - lane - 80*wid

    const bool is_l0 = (lane == 0);
    const bool is_w1 = (wid == 1);
    float* ringw = &ring[wid * 4096];     // own plane (unconditional write)

    __syncthreads();                      // ring init visible

    for (int g = 0; g < NG; ++g) {
        if      (g == 4)  xq = xc1;       // chunk switch at s = 64,128,192
        else if (g == 8)  xq = xc2;
        else if (g == 12) xq = xc3;

        if (is_w1) {                      // seam prefetch: consumed THIS group
            const int base = 16 * g - 17;
            #pragma unroll
            for (int k = 0; k < 16; ++k)
                pk[k] = ring[((base + k) & 63) * 64 + 63];   // plane 0, broadcast
        }

        const int sb = (16 * g) & 63;     // slot base for this group

        #pragma unroll
        for (int k = 0; k < 16; ++k) {
            ++t;
            const bool valid = (unsigned)t < (unsigned)T_LEN;

            float alt = is_w1 ? pk[k] : xq;          // ready since group top
            float shifted = dpp_wave_shr1(h);        // chain start
            float in = is_l0 ? alt : shifted;

            float u_r  = fmaf(wi_r, in, c_r);
            float u_z  = fmaf(wi_z, in, c_z);
            float u_n0 = fmaf(wi_n, in, bi_n);
            float r = rcp1p(ex2(u_r));
            float z = rcp1p(ex2(u_z));
            z = valid ? z : 1.0f;                    // freeze: two_omz=0, zh_m=h
            float two_omz = fmaf(-2.0f, z, 2.0f);    // 2*(1-z), off-chain
            float zh_m    = fmaf(z, h, z - 1.0f);    // z*h - (1-z), off-chain
            float s_n = rcp1p(ex2(fmaf(r, g_n, u_n0)));
            h = fmaf(s_n, two_omz, zh_m);            // (1-z)*(2*s_n-1) + z*h

            c_r = fmaf(wh_r, h, b_r);                // off input-critical chain
            c_z = fmaf(wh_z, h, b_z);
            g_n = fmaf(wh_n, h, bh_n);

            ringw[((sb + k) & 63) * 64 + lane] = h;  // publish (fire-and-forget)

            // output conveyor: rotate, inject layer-127 h at lane 63
            float rot = dpp_wave_rol1(ov);
            ov = (lane == 63) ? h : rot;
            xq = dpp_wave_rol1(xq);                  // x conveyor advance

            if (k == 14) {                           // stores at s=206,270,334,398
                if (is_w1 && (g & 3) == 0 && g >= 12)
                    out[16 * g - 192 + lane] = ov;   // coalesced 64-lane store
            }
        }
        __syncthreads();                             // bounds wave drift (<16 steps)
    }
}

extern "C" void kernel_launch(void* const* d_in, const int* in_sizes, int n_in,
                              void* d_out, int out_size, void* d_ws, size_t ws_size,
                              hipStream_t stream) {
    const float* x    = (const float*)d_in[0];  // [1,256]
    const float* w_ih = (const float*)d_in[1];  // [128,3,1]
    const float* w_hh = (const float*)d_in[2];  // [128,3,1]
    const float* b_ih = (const float*)d_in[3];  // [128,3]
    const float* b_hh = (const float*)d_in[4];  // [128,3]
    float* out = (float*)d_out;                 // [1,256]

    gru_stack_wavefront<<<1, 128, 0, stream>>>(x, w_ih, w_hh, b_ih, b_hh, out);
}

// Round 16
// 93.053 us; speedup vs baseline: 1.3599x; 1.0138x over previous
//
#include <hip/hip_runtime.h>

#define T_LEN 256
#define NG 25              // 25 groups x 16 steps = 400 steps (need s_max = 398)

__device__ __forceinline__ float ex2(float x) { return __builtin_amdgcn_exp2f(x); }
__device__ __forceinline__ float rcp1p(float e) { return __builtin_amdgcn_rcpf(1.0f + e); }

// wave_shr:1 (0x138): lane i <- lane i-1 (lane 0 keeps own). VALU pipe.
__device__ __forceinline__ float dpp_wave_shr1(float v) {
    int i = __float_as_int(v);
    return __int_as_float(__builtin_amdgcn_update_dpp(i, i, 0x138, 0xF, 0xF, false));
}
// wave_rol:1 (0x134): lane i <- lane (i+1)%64.
__device__ __forceinline__ float dpp_wave_rol1(float v) {
    int i = __float_as_int(v);
    return __int_as_float(__builtin_amdgcn_update_dpp(i, i, 0x134, 0xF, 0xF, false));
}

// R15 skeleton with ONE change: per-step ring ds_write replaced by a
// per-GROUP conveyor dump (the output conveyor ov already holds the last 64
// values of h(63): injected at lane 63, rotated by wave_rol:1 each step).
// At end of group g, lane i writes ov -> slot (16g-48+i)&63 (one ds_write).
//  - w1's group-top reads (steps 16g-17..16g-2) are covered by the
//    end-of-(g-1) dump (steps 16g-64..16g-1), barrier-ordered.
//  - end-of-g dump rewrites some read slots with BITWISE-IDENTICAL values
//    (conveyor history is write-once); its new steps (16g..16g+15) map to
//    slots disjoint from the read slots => races are disjoint-or-identical
//    => deterministic. True overwrite (step+64) lands >=2 barriers later.
// TWO waves, 1 layer/lane. cell (l,t) at step s = t + l + 16*(l>=64).
//  - in-wave handoff: DPP wave_shr:1 (exact, prev-step h).
//  - folded h-update: h' = s_n*(2-2z) + (z*h + z-1); two_omz/zh_m off-chain.
//  - validity z:=1 freeze => h'==h exactly (ring zero-inited; no NaN).
//  - x conveyor (wave_rol:1, 4 chunks, switch at g=4,8,12).
//  - out: conveyor (lane-63 inject) on w1; coalesced 64-lane stores at
//    s = 206,270,334,398 (k==14, g=12,16,20,24), out base = 16g-192.
__global__ __launch_bounds__(128, 1) void gru_stack_wavefront(
    const float* __restrict__ x,
    const float* __restrict__ w_ih,
    const float* __restrict__ w_hh,
    const float* __restrict__ b_ih,
    const float* __restrict__ b_hh,
    float* __restrict__ out)
{
    __shared__ float ring[2 * 64];        // [wid][slot]: h(63) / h(127) history
    const int tid  = threadIdx.x;         // 0..127 == layer index
    const int lane = tid & 63;
    const int wid  = tid >> 6;

    ring[tid] = 0.0f;                     // zero-init both planes

    const float L1 = -1.4426950408889634f;   // -log2(e)
    const float L2 = -2.8853900817779268f;   // -2*log2(e)

    const float wi_r = L1 * w_ih[3 * tid + 0], wh_r = L1 * w_hh[3 * tid + 0];
    const float b_r  = L1 * (b_ih[3 * tid + 0] + b_hh[3 * tid + 0]);
    const float wi_z = L1 * w_ih[3 * tid + 1], wh_z = L1 * w_hh[3 * tid + 1];
    const float b_z  = L1 * (b_ih[3 * tid + 1] + b_hh[3 * tid + 1]);
    const float wi_n = L2 * w_ih[3 * tid + 2], bi_n = L2 * b_ih[3 * tid + 2];
    const float wh_n = L2 * w_hh[3 * tid + 2], bh_n = L2 * b_hh[3 * tid + 2];

    float xc0 = x[lane];
    float xc1 = x[lane + 64];
    float xc2 = x[lane + 128];
    float xc3 = x[lane + 192];

    float h = 0.0f;
    float c_r = b_r, c_z = b_z, g_n = bh_n;

    float pk[16];
    #pragma unroll
    for (int k = 0; k < 16; ++k) pk[k] = 0.0f;

    float ov = 0.0f;                      // conveyor: w0 feeds seam, w1 feeds out
    float xq = xc0;                       // x conveyor (wave0's is consumed)
    int t = -lane - 80 * wid - 1;         // ++ at step top -> t = s - lane - 80*wid

    const bool is_l0 = (lane == 0);
    const bool is_w1 = (wid == 1);
    float* ringw = &ring[wid * 64];       // own plane (w1's never read; branch-free)

    __syncthreads();                      // ring init visible

    for (int g = 0; g < NG; ++g) {
        if      (g == 4)  xq = xc1;       // chunk switch at s = 64,128,192
        else if (g == 8)  xq = xc2;
        else if (g == 12) xq = xc3;

        if (is_w1) {                      // seam prefetch: consumed THIS group
            const int base = 16 * g - 17;
            #pragma unroll
            for (int k = 0; k < 16; ++k)
                pk[k] = ring[(base + k) & 63];       // plane 0, broadcast read
        }

        #pragma unroll
        for (int k = 0; k < 16; ++k) {
            ++t;
            const bool valid = (unsigned)t < (unsigned)T_LEN;

            float alt = is_w1 ? pk[k] : xq;          // ready since group top
            float shifted = dpp_wave_shr1(h);        // chain start
            float in = is_l0 ? alt : shifted;

            float u_r  = fmaf(wi_r, in, c_r);
            float u_z  = fmaf(wi_z, in, c_z);
            float u_n0 = fmaf(wi_n, in, bi_n);
            float r = rcp1p(ex2(u_r));
            float z = rcp1p(ex2(u_z));
            z = valid ? z : 1.0f;                    // freeze: two_omz=0, zh_m=h
            float two_omz = fmaf(-2.0f, z, 2.0f);    // 2*(1-z), off-chain
            float zh_m    = fmaf(z, h, z - 1.0f);    // z*h - (1-z), off-chain
            float s_n = rcp1p(ex2(fmaf(r, g_n, u_n0)));
            h = fmaf(s_n, two_omz, zh_m);            // (1-z)*(2*s_n-1) + z*h

            c_r = fmaf(wh_r, h, b_r);                // off input-critical chain
            c_z = fmaf(wh_z, h, b_z);
            g_n = fmaf(wh_n, h, bh_n);

            // conveyor: rotate, inject this wave's top-layer h at lane 63
            float rot = dpp_wave_rol1(ov);
            ov = (lane == 63) ? h : rot;
            xq = dpp_wave_rol1(xq);                  // x conveyor advance

            if (k == 14) {                           // stores at s=206,270,334,398
                if (is_w1 && (g & 3) == 0 && g >= 12)
                    out[16 * g - 192 + lane] = ov;   // coalesced 64-lane store
            }
        }

        // group-end conveyor dump: lane i holds h(top, 16g-48+i) -> slot&63.
        // Disjoint-or-identical with w1's reads (proof in header). One write.
        ringw[(16 * g + 16 + lane) & 63] = ov;

        __syncthreads();                             // bounds wave drift (<16 steps)
    }
}

extern "C" void kernel_launch(void* const* d_in, const int* in_sizes, int n_in,
                              void* d_out, int out_size, void* d_ws, size_t ws_size,
                              hipStream_t stream) {
    const float* x    = (const float*)d_in[0];  // [1,256]
    const float* w_ih = (const float*)d_in[1];  // [128,3,1]
    const float* w_hh = (const float*)d_in[2];  // [128,3,1]
    const float* b_ih = (const float*)d_in[3];  // [128,3]
    const float* b_hh = (const float*)d_in[4];  // [128,3]
    float* out = (float*)d_out;                 // [1,256]

    gru_stack_wavefront<<<1, 128, 0, stream>>>(x, w_ih, w_hh, b_ih, b_hh, out);
}

// Round 17
// 88.199 us; speedup vs baseline: 1.4347x; 1.0550x over previous
//
#include <hip/hip_runtime.h>

#define T_LEN 256
#define NG 25              // 25 groups x 16 steps = 400 steps (need s_max = 398)

__device__ __forceinline__ float ex2(float x) { return __builtin_amdgcn_exp2f(x); }
__device__ __forceinline__ float rcp1p(float e) { return __builtin_amdgcn_rcpf(1.0f + e); }

// Shift-with-fill: lane i <- lane i-1 (wave_shr:1, 0x138); lane 0 (no valid
// source, bound_ctrl=false) keeps OLD = fill. One instruction on the chain.
__device__ __forceinline__ float dpp_shr1_fill(float fill, float v) {
    int f = __float_as_int(fill), i = __float_as_int(v);
    return __int_as_float(__builtin_amdgcn_update_dpp(f, i, 0x138, 0xF, 0xF, false));
}
// wave_rol:1 (0x134): lane i <- lane (i+1)%64 (output/seam conveyor).
__device__ __forceinline__ float dpp_wave_rol1(float v) {
    int i = __float_as_int(v);
    return __int_as_float(__builtin_amdgcn_update_dpp(i, i, 0x134, 0xF, 0xF, false));
}

// R16 skeleton with ONE mechanism change: the step-head input path
// (2 cndmasks + dpp) collapses to a single dpp-with-old-fill:
//     in = update_dpp(old = pk[k], src = h, wave_shr:1)
// Lane 0 gets the group-top prefetched seam feed (w0: x[s] from sx LDS,
// w1: h(63, s-17) from the conveyor-dumped ring), lanes 1-63 get the
// neighbor's prev-step h. The x register conveyor + chunk switches are
// deleted; both waves now do a symmetric group-top broadcast prefetch
// (w1 already paid this while w0 idled into the barrier -> zero wall cost).
// TWO waves, 1 layer/lane. cell (l,t) at step s = t + l + 16*(l>=64).
//  - folded h-update: h' = s_n*(2-2z) + (z*h + z-1); two_omz/zh_m off-chain.
//  - validity z:=1 freeze => h'==h exactly (sx wrap past 255 feeds only
//    frozen lanes; ring zero-inited; no NaN).
//  - seam ring: per-GROUP conveyor dump (R16): at end of group g lane i
//    writes ov (= h(top, 16g-48+i)) -> slot (16g+16+i)&63; reads are
//    barrier-covered, races disjoint-or-identical, overwrite 2 barriers away.
//  - out: conveyor (lane-63 inject) on w1; coalesced 64-lane stores at
//    s = 206,270,334,398 (k==14, g=12,16,20,24), out base = 16g-192.
__global__ __launch_bounds__(128, 1) void gru_stack_wavefront(
    const float* __restrict__ x,
    const float* __restrict__ w_ih,
    const float* __restrict__ w_hh,
    const float* __restrict__ b_ih,
    const float* __restrict__ b_hh,
    float* __restrict__ out)
{
    __shared__ float ring[2 * 64];        // [wid][slot]: h(63) / h(127) history
    __shared__ float sx[T_LEN];
    const int tid  = threadIdx.x;         // 0..127 == layer index
    const int lane = tid & 63;
    const int wid  = tid >> 6;

    ring[tid] = 0.0f;                     // zero-init both planes
    sx[tid] = x[tid];
    sx[tid + 128] = x[tid + 128];

    const float L1 = -1.4426950408889634f;   // -log2(e)
    const float L2 = -2.8853900817779268f;   // -2*log2(e)

    const float wi_r = L1 * w_ih[3 * tid + 0], wh_r = L1 * w_hh[3 * tid + 0];
    const float b_r  = L1 * (b_ih[3 * tid + 0] + b_hh[3 * tid + 0]);
    const float wi_z = L1 * w_ih[3 * tid + 1], wh_z = L1 * w_hh[3 * tid + 1];
    const float b_z  = L1 * (b_ih[3 * tid + 1] + b_hh[3 * tid + 1]);
    const float wi_n = L2 * w_ih[3 * tid + 2], bi_n = L2 * b_ih[3 * tid + 2];
    const float wh_n = L2 * w_hh[3 * tid + 2], bh_n = L2 * b_hh[3 * tid + 2];

    float h = 0.0f;
    float c_r = b_r, c_z = b_z, g_n = bh_n;

    float pk[16];
    #pragma unroll
    for (int k = 0; k < 16; ++k) pk[k] = 0.0f;

    float ov = 0.0f;                      // conveyor: w0 feeds seam dump, w1 out
    int t = -lane - 80 * wid - 1;         // ++ at step top -> t = s - lane - 80*wid

    const bool is_w1 = (wid == 1);
    float* ringw = &ring[wid * 64];       // own plane (w1's never read)

    __syncthreads();                      // ring + sx init visible

    for (int g = 0; g < NG; ++g) {
        // group-top seam-feed prefetch (broadcast reads, consumed this group)
        if (is_w1) {
            const int base = 16 * g - 17;
            #pragma unroll
            for (int k = 0; k < 16; ++k)
                pk[k] = ring[(base + k) & 63];       // h(63, s-17)
        } else {
            #pragma unroll
            for (int k = 0; k < 16; ++k)
                pk[k] = sx[(16 * g + k) & (T_LEN - 1)];  // x[s] (wrap: frozen lanes)
        }

        #pragma unroll
        for (int k = 0; k < 16; ++k) {
            ++t;
            const bool valid = (unsigned)t < (unsigned)T_LEN;

            // input path: ONE on-chain instruction (lane0 <- pk[k], else shift)
            float in = dpp_shr1_fill(pk[k], h);

            float u_r  = fmaf(wi_r, in, c_r);
            float u_z  = fmaf(wi_z, in, c_z);
            float u_n0 = fmaf(wi_n, in, bi_n);
            float r = rcp1p(ex2(u_r));
            float z = rcp1p(ex2(u_z));
            z = valid ? z : 1.0f;                    // freeze: two_omz=0, zh_m=h
            float two_omz = fmaf(-2.0f, z, 2.0f);    // 2*(1-z), off-chain
            float zh_m    = fmaf(z, h, z - 1.0f);    // z*h - (1-z), off-chain
            float s_n = rcp1p(ex2(fmaf(r, g_n, u_n0)));
            h = fmaf(s_n, two_omz, zh_m);            // (1-z)*(2*s_n-1) + z*h

            c_r = fmaf(wh_r, h, b_r);                // off input-critical chain
            c_z = fmaf(wh_z, h, b_z);
            g_n = fmaf(wh_n, h, bh_n);

            // conveyor: rotate, inject this wave's top-layer h at lane 63
            float rot = dpp_wave_rol1(ov);
            ov = (lane == 63) ? h : rot;

            if (k == 14) {                           // stores at s=206,270,334,398
                if (is_w1 && (g & 3) == 0 && g >= 12)
                    out[16 * g - 192 + lane] = ov;   // coalesced 64-lane store
            }
        }

        // group-end conveyor dump: lane i holds h(top, 16g-48+i) -> slot&63.
        // Disjoint-or-identical with w1's reads; overwrite >=2 barriers away.
        ringw[(16 * g + 16 + lane) & 63] = ov;

        __syncthreads();                             // bounds wave drift (<16 steps)
    }
}

extern "C" void kernel_launch(void* const* d_in, const int* in_sizes, int n_in,
                              void* d_out, int out_size, void* d_ws, size_t ws_size,
                              hipStream_t stream) {
    const float* x    = (const float*)d_in[0];  // [1,256]
    const float* w_ih = (const float*)d_in[1];  // [128,3,1]
    const float* w_hh = (const float*)d_in[2];  // [128,3,1]
    const float* b_ih = (const float*)d_in[3];  // [128,3]
    const float* b_hh = (const float*)d_in[4];  // [128,3]
    float* out = (float*)d_out;                 // [1,256]

    gru_stack_wavefront<<<1, 128, 0, stream>>>(x, w_ih, w_hh, b_ih, b_hh, out);
}

// Round 18
// 87.185 us; speedup vs baseline: 1.4514x; 1.0116x over previous
//
#include <hip/hip_runtime.h>

#define T_LEN 256
#define NG 25              // 25 groups x 16 steps = 400 steps (need s_max = 398)

__device__ __forceinline__ float ex2(float x) { return __builtin_amdgcn_exp2f(x); }
__device__ __forceinline__ float rcp1p(float e) { return __builtin_amdgcn_rcpf(1.0f + e); }

// Shift-with-fill: lane i <- lane i-1 (wave_shr:1, 0x138); lane 0 (sourceless,
// bound_ctrl=false) keeps OLD = fill. One instruction on the chain.
__device__ __forceinline__ float dpp_shr1_fill(float fill, float v) {
    int f = __float_as_int(fill), i = __float_as_int(v);
    return __int_as_float(__builtin_amdgcn_update_dpp(f, i, 0x138, 0xF, 0xF, false));
}
// Shift-with-fill the other way: lane i <- lane i+1 (wave_shl:1, 0x130);
// lane 63 (sourceless) keeps OLD = fill. Fuses the conveyor rotate+inject.
__device__ __forceinline__ float dpp_shl1_fill(float fill, float v) {
    int f = __float_as_int(fill), i = __float_as_int(v);
    return __int_as_float(__builtin_amdgcn_update_dpp(f, i, 0x130, 0xF, 0xF, false));
}

// R17 skeleton + two issue deletions:
//  (1) output conveyor fused: ov = dpp(old=h, src=ov, wave_shl:1)
//      == rotate-down + inject h at lane 63, one instruction.
//  (2) ramp/steady split at the g-LOOP level (two sequential loops, no
//      per-group branch): freeze (z:=1 when t<0..255 out of range) is only
//      needed for ramp-IN exactness (h must stay 0 until thaw; all lanes of
//      both waves thawed by s=143 = end of group 8). Ramp-OUT garbage is
//      never consumed: in-wave dpp reads lag valid production by 1 step;
//      ring reads past production step 318 feed only invalid w1 lanes; the
//      last store (s=398) reads h(127, 192..255), all valid.
// TWO waves, 1 layer/lane. cell (l,t) at step s = t + l + 16*(l>=64).
//  - step-head input: in = dpp(old=pk[k], src=h, wave_shr:1)  (R17).
//  - folded h-update: h' = s_n*(2-2z) + (z*h + z-1); two_omz/zh_m off-chain.
//  - seam ring: per-GROUP conveyor dump; reads barrier-covered, races
//    disjoint-or-identical, overwrite >=2 barriers away (R16 proof).
//  - out: coalesced 64-lane stores at s=206,270,334,398 (k==14, g=12,16,20,24).
__global__ __launch_bounds__(128, 1) void gru_stack_wavefront(
    const float* __restrict__ x,
    const float* __restrict__ w_ih,
    const float* __restrict__ w_hh,
    const float* __restrict__ b_ih,
    const float* __restrict__ b_hh,
    float* __restrict__ out)
{
    __shared__ float ring[2 * 64];        // [wid][slot]: h(63) / h(127) history
    __shared__ float sx[T_LEN];
    const int tid  = threadIdx.x;         // 0..127 == layer index
    const int lane = tid & 63;
    const int wid  = tid >> 6;

    ring[tid] = 0.0f;                     // zero-init both planes
    sx[tid] = x[tid];
    sx[tid + 128] = x[tid + 128];

    const float L1 = -1.4426950408889634f;   // -log2(e)
    const float L2 = -2.8853900817779268f;   // -2*log2(e)

    const float wi_r = L1 * w_ih[3 * tid + 0], wh_r = L1 * w_hh[3 * tid + 0];
    const float b_r  = L1 * (b_ih[3 * tid + 0] + b_hh[3 * tid + 0]);
    const float wi_z = L1 * w_ih[3 * tid + 1], wh_z = L1 * w_hh[3 * tid + 1];
    const float b_z  = L1 * (b_ih[3 * tid + 1] + b_hh[3 * tid + 1]);
    const float wi_n = L2 * w_ih[3 * tid + 2], bi_n = L2 * b_ih[3 * tid + 2];
    const float wh_n = L2 * w_hh[3 * tid + 2], bh_n = L2 * b_hh[3 * tid + 2];

    float h = 0.0f;
    float c_r = b_r, c_z = b_z, g_n = bh_n;

    float pk[16];
    #pragma unroll
    for (int k = 0; k < 16; ++k) pk[k] = 0.0f;

    float ov = 0.0f;                      // conveyor: w0 feeds seam dump, w1 out
    int t = -lane - 80 * wid - 1;         // ++ at step top (ramp loop only)

    const bool is_w1 = (wid == 1);
    float* ringw = &ring[wid * 64];       // own plane (w1's never read)

    __syncthreads();                      // ring + sx init visible

    // ---------- ramp loop: g = 0..8 (s = 0..143), freeze active ----------
    for (int g = 0; g < 9; ++g) {
        if (is_w1) {
            const int base = 16 * g - 17;
            #pragma unroll
            for (int k = 0; k < 16; ++k)
                pk[k] = ring[(base + k) & 63];           // h(63, s-17)
        } else {
            #pragma unroll
            for (int k = 0; k < 16; ++k)
                pk[k] = sx[16 * g + k];                  // x[s], s <= 143
        }

        #pragma unroll
        for (int k = 0; k < 16; ++k) {
            ++t;
            const bool valid = (unsigned)t < (unsigned)T_LEN;

            float in = dpp_shr1_fill(pk[k], h);          // one-instr input path

            float u_r  = fmaf(wi_r, in, c_r);
            float u_z  = fmaf(wi_z, in, c_z);
            float u_n0 = fmaf(wi_n, in, bi_n);
            float r = rcp1p(ex2(u_r));
            float z = rcp1p(ex2(u_z));
            z = valid ? z : 1.0f;                        // freeze: h' == h == 0
            float two_omz = fmaf(-2.0f, z, 2.0f);
            float zh_m    = fmaf(z, h, z - 1.0f);
            float s_n = rcp1p(ex2(fmaf(r, g_n, u_n0)));
            h = fmaf(s_n, two_omz, zh_m);

            c_r = fmaf(wh_r, h, b_r);
            c_z = fmaf(wh_z, h, b_z);
            g_n = fmaf(wh_n, h, bh_n);

            ov = dpp_shl1_fill(h, ov);                   // fused rotate+inject
        }
        ringw[(16 * g + 16 + lane) & 63] = ov;           // group-end dump
        __syncthreads();
    }

    // ---------- steady loop: g = 9..24, freeze-free (ramp-out garbage
    // provably never consumed; see header) ----------
    for (int g = 9; g < NG; ++g) {
        if (is_w1) {
            const int base = 16 * g - 17;
            #pragma unroll
            for (int k = 0; k < 16; ++k)
                pk[k] = ring[(base + k) & 63];           // h(63, s-17)
        } else {
            #pragma unroll
            for (int k = 0; k < 16; ++k)
                pk[k] = sx[(16 * g + k) & (T_LEN - 1)];  // x[s] (wrap: dead lanes)
        }

        #pragma unroll
        for (int k = 0; k < 16; ++k) {
            float in = dpp_shr1_fill(pk[k], h);          // one-instr input path

            float u_r  = fmaf(wi_r, in, c_r);
            float u_z  = fmaf(wi_z, in, c_z);
            float u_n0 = fmaf(wi_n, in, bi_n);
            float r = rcp1p(ex2(u_r));
            float z = rcp1p(ex2(u_z));
            float two_omz = fmaf(-2.0f, z, 2.0f);
            float zh_m    = fmaf(z, h, z - 1.0f);
            float s_n = rcp1p(ex2(fmaf(r, g_n, u_n0)));
            h = fmaf(s_n, two_omz, zh_m);

            c_r = fmaf(wh_r, h, b_r);
            c_z = fmaf(wh_z, h, b_z);
            g_n = fmaf(wh_n, h, bh_n);

            ov = dpp_shl1_fill(h, ov);                   // fused rotate+inject

            if (k == 14) {                               // s = 206,270,334,398
                if (is_w1 && (g & 3) == 0 && g >= 12)
                    out[16 * g - 192 + lane] = ov;       // coalesced store
            }
        }
        ringw[(16 * g + 16 + lane) & 63] = ov;           // group-end dump
        __syncthreads();
    }
}

extern "C" void kernel_launch(void* const* d_in, const int* in_sizes, int n_in,
                              void* d_out, int out_size, void* d_ws, size_t ws_size,
                              hipStream_t stream) {
    const float* x    = (const float*)d_in[0];  // [1,256]
    const float* w_ih = (const float*)d_in[1];  // [128,3,1]
    const float* w_hh = (const float*)d_in[2];  // [128,3,1]
    const float* b_ih = (const float*)d_in[3];  // [128,3]
    const float* b_hh = (const float*)d_in[4];  // [128,3]
    float* out = (float*)d_out;                 // [1,256]

    gru_stack_wavefront<<<1, 128, 0, stream>>>(x, w_ih, w_hh, b_ih, b_hh, out);
}

// Round 19
// 83.450 us; speedup vs baseline: 1.5163x; 1.0447x over previous
//
#include <hip/hip_runtime.h>

#define T_LEN 256
#define NG 25              // 25 groups x 16 steps = 400 steps (need s_max = 398)

__device__ __forceinline__ float ex2(float x) { return __builtin_amdgcn_exp2f(x); }
__device__ __forceinline__ float rcpf_(float x) { return __builtin_amdgcn_rcpf(x); }

// Shift-with-fill: lane i <- lane i-1 (wave_shr:1, 0x138); lane 0 (sourceless,
// bound_ctrl=false) keeps OLD = fill. One instruction on the chain.
__device__ __forceinline__ float dpp_shr1_fill(float fill, float v) {
    int f = __float_as_int(fill), i = __float_as_int(v);
    return __int_as_float(__builtin_amdgcn_update_dpp(f, i, 0x138, 0xF, 0xF, false));
}
// Shift-with-fill the other way: lane i <- lane i+1 (wave_shl:1, 0x130);
// lane 63 (sourceless) keeps OLD = fill. Fuses the conveyor rotate+inject.
__device__ __forceinline__ float dpp_shl1_fill(float fill, float v) {
    int f = __float_as_int(fill), i = __float_as_int(v);
    return __int_as_float(__builtin_amdgcn_update_dpp(f, i, 0x130, 0xF, 0xF, false));
}

// R18 skeleton + ONE change: shared-denominator h-update fold.
//   z = 1/(1+E_z), n = (1-E_n)/(1+E_n)  (E_z = exp2(u_z'), E_n = exp2(un'))
//   h' = (1-z)n + zh = [E_z(1-E_n) + h(1+E_n)] / [(1+E_n)(1+E_z)]
// -> ONE rcp (of the product) replaces the two tail rcps: 5 transcendentals
// per step instead of 6; -1 add; +1 mul. Freeze ports exactly as E_z := 0
// (=> num = h*t1, den = t1, h' = h*t1*rcp(t1); ramp-in h==0 stays 0 EXACTLY).
// Ramp-out inf/NaN in dead lanes is contained: valid consumers only read
// valid-produced values (R18 proof); ring/conveyor garbage feeds only
// invalid cells whose outputs are never consumed.
// TWO waves, 1 layer/lane. cell (l,t) at step s = t + l + 16*(l>=64).
//  - step-head input: in = dpp(old=pk[k], src=h, wave_shr:1)  (R17).
//  - output conveyor fused: ov = dpp(old=h, src=ov, wave_shl:1) (R18).
//  - ramp loop g=0..8 (freeze), steady loop g=9..24 (freeze-free) (R18).
//  - seam ring: per-GROUP conveyor dump; reads barrier-covered, races
//    disjoint-or-identical, overwrite >=2 barriers away (R16 proof).
//  - out: coalesced 64-lane stores at s=206,270,334,398 (k==14, g=12,16,20,24).
__global__ __launch_bounds__(128, 1) void gru_stack_wavefront(
    const float* __restrict__ x,
    const float* __restrict__ w_ih,
    const float* __restrict__ w_hh,
    const float* __restrict__ b_ih,
    const float* __restrict__ b_hh,
    float* __restrict__ out)
{
    __shared__ float ring[2 * 64];        // [wid][slot]: h(63) / h(127) history
    __shared__ float sx[T_LEN];
    const int tid  = threadIdx.x;         // 0..127 == layer index
    const int lane = tid & 63;
    const int wid  = tid >> 6;

    ring[tid] = 0.0f;                     // zero-init both planes
    sx[tid] = x[tid];
    sx[tid + 128] = x[tid + 128];

    const float L1 = -1.4426950408889634f;   // -log2(e)
    const float L2 = -2.8853900817779268f;   // -2*log2(e)

    const float wi_r = L1 * w_ih[3 * tid + 0], wh_r = L1 * w_hh[3 * tid + 0];
    const float b_r  = L1 * (b_ih[3 * tid + 0] + b_hh[3 * tid + 0]);
    const float wi_z = L1 * w_ih[3 * tid + 1], wh_z = L1 * w_hh[3 * tid + 1];
    const float b_z  = L1 * (b_ih[3 * tid + 1] + b_hh[3 * tid + 1]);
    const float wi_n = L2 * w_ih[3 * tid + 2], bi_n = L2 * b_ih[3 * tid + 2];
    const float wh_n = L2 * w_hh[3 * tid + 2], bh_n = L2 * b_hh[3 * tid + 2];

    float h = 0.0f;
    float c_r = b_r, c_z = b_z, g_n = bh_n;

    float pk[16];
    #pragma unroll
    for (int k = 0; k < 16; ++k) pk[k] = 0.0f;

    float ov = 0.0f;                      // conveyor: w0 feeds seam dump, w1 out
    int t = -lane - 80 * wid - 1;         // ++ at step top (ramp loop only)

    const bool is_w1 = (wid == 1);
    float* ringw = &ring[wid * 64];       // own plane (w1's never read)

    __syncthreads();                      // ring + sx init visible

    // ---------- ramp loop: g = 0..8 (s = 0..143), freeze active ----------
    for (int g = 0; g < 9; ++g) {
        if (is_w1) {
            const int base = 16 * g - 17;
            #pragma unroll
            for (int k = 0; k < 16; ++k)
                pk[k] = ring[(base + k) & 63];           // h(63, s-17)
        } else {
            #pragma unroll
            for (int k = 0; k < 16; ++k)
                pk[k] = sx[16 * g + k];                  // x[s], s <= 143
        }

        #pragma unroll
        for (int k = 0; k < 16; ++k) {
            ++t;
            const bool valid = (unsigned)t < (unsigned)T_LEN;

            float in = dpp_shr1_fill(pk[k], h);          // one-instr input path

            float u_r  = fmaf(wi_r, in, c_r);
            float u_z  = fmaf(wi_z, in, c_z);
            float u_n0 = fmaf(wi_n, in, bi_n);
            float r  = rcpf_(1.0f + ex2(u_r));
            float Ez = ex2(u_z);
            Ez = valid ? Ez : 0.0f;                      // freeze: h' = h (exact at h=0)
            float En = ex2(fmaf(r, g_n, u_n0));
            float t1  = 1.0f + En;                       // (1+E_n)
            float den = fmaf(Ez, t1, t1);                // (1+E_n)(1+E_z)
            float bb  = fmaf(-Ez, En, Ez);               // E_z(1-E_n), off-chain
            float num = fmaf(h, t1, bb);                 // h(1+E_n) + E_z(1-E_n)
            h = num * rcpf_(den);

            c_r = fmaf(wh_r, h, b_r);
            c_z = fmaf(wh_z, h, b_z);
            g_n = fmaf(wh_n, h, bh_n);

            ov = dpp_shl1_fill(h, ov);                   // fused rotate+inject
        }
        ringw[(16 * g + 16 + lane) & 63] = ov;           // group-end dump
        __syncthreads();
    }

    // ---------- steady loop: g = 9..24, freeze-free (ramp-out garbage
    // provably never consumed; NaN contained — see header) ----------
    for (int g = 9; g < NG; ++g) {
        if (is_w1) {
            const int base = 16 * g - 17;
            #pragma unroll
            for (int k = 0; k < 16; ++k)
                pk[k] = ring[(base + k) & 63];           // h(63, s-17)
        } else {
            #pragma unroll
            for (int k = 0; k < 16; ++k)
                pk[k] = sx[(16 * g + k) & (T_LEN - 1)];  // x[s] (wrap: dead lanes)
        }

        #pragma unroll
        for (int k = 0; k < 16; ++k) {
            float in = dpp_shr1_fill(pk[k], h);          // one-instr input path

            float u_r  = fmaf(wi_r, in, c_r);
            float u_z  = fmaf(wi_z, in, c_z);
            float u_n0 = fmaf(wi_n, in, bi_n);
            float r  = rcpf_(1.0f + ex2(u_r));
            float Ez = ex2(u_z);
            float En = ex2(fmaf(r, g_n, u_n0));
            float t1  = 1.0f + En;
            float den = fmaf(Ez, t1, t1);
            float bb  = fmaf(-Ez, En, Ez);
            float num = fmaf(h, t1, bb);
            h = num * rcpf_(den);

            c_r = fmaf(wh_r, h, b_r);
            c_z = fmaf(wh_z, h, b_z);
            g_n = fmaf(wh_n, h, bh_n);

            ov = dpp_shl1_fill(h, ov);                   // fused rotate+inject

            if (k == 14) {                               // s = 206,270,334,398
                if (is_w1 && (g & 3) == 0 && g >= 12)
                    out[16 * g - 192 + lane] = ov;       // coalesced store
            }
        }
        ringw[(16 * g + 16 + lane) & 63] = ov;           // group-end dump
        __syncthreads();
    }
}

extern "C" void kernel_launch(void* const* d_in, const int* in_sizes, int n_in,
                              void* d_out, int out_size, void* d_ws, size_t ws_size,
                              hipStream_t stream) {
    const float* x    = (const float*)d_in[0];  // [1,256]
    const float* w_ih = (const float*)d_in[1];  // [128,3,1]
    const float* w_hh = (const float*)d_in[2];  // [128,3,1]
    const float* b_ih = (const float*)d_in[3];  // [128,3]
    const float* b_hh = (const float*)d_in[4];  // [128,3]
    float* out = (float*)d_out;                 // [1,256]

    gru_stack_wavefront<<<1, 128, 0, stream>>>(x, w_ih, w_hh, b_ih, b_hh, out);
}